// Round 10
// baseline (1036.782 us; speedup 1.0000x reference)
//
#include <hip/hip_runtime.h>

#define H 128
#define KV 256

typedef short bf16x8 __attribute__((ext_vector_type(8)));
typedef float f32x4 __attribute__((ext_vector_type(4)));
union FragU { uint4 u; bf16x8 s; };

__device__ __forceinline__ float bf2f(unsigned short u) {
  return __uint_as_float(((unsigned)u) << 16);
}
__device__ __forceinline__ unsigned short f2bf(float f) {
  unsigned b = __float_as_uint(f);
  b += 0x7FFFu + ((b >> 16) & 1u);   // round-to-nearest-even
  return (unsigned short)(b >> 16);
}
// rad6 = unique entries of the symmetric radial matrix:
// [00,11,22,01,02,12]; fold maps pa/pb pair off-diagonal rows.
__device__ __forceinline__ void rad6_from_cd(const float cd[9], float r6[6]) {
  r6[0] = cd[0]*cd[0] + cd[1]*cd[1] + cd[2]*cd[2];
  r6[1] = cd[3]*cd[3] + cd[4]*cd[4] + cd[5]*cd[5];
  r6[2] = cd[6]*cd[6] + cd[7]*cd[7] + cd[8]*cd[8];
  r6[3] = cd[0]*cd[3] + cd[1]*cd[4] + cd[2]*cd[5];
  r6[4] = cd[0]*cd[6] + cd[1]*cd[7] + cd[2]*cd[8];
  r6[5] = cd[3]*cd[6] + cd[4]*cd[7] + cd[5]*cd[8];
}
__constant__ int c_pa[6] = {0,4,8,1,2,5};
__constant__ int c_pb[6] = {0,0,0,3,6,7};

__global__ __launch_bounds__(256) void k_zero(float* __restrict__ p, int n) {
  int i = blockIdx.x * 256 + threadIdx.x;
  if (i < n) p[i] = 0.f;
}
__global__ __launch_bounds__(256) void k_sentinel(float* __restrict__ out, int n) {
  int i = blockIdx.x * 256 + threadIdx.x;
  if (i < n) out[i] = 1000.0f;
}

// pack Wc1 (128x512 fp32) into bf16 fragment order (verified R5-R9)
__global__ __launch_bounds__(256) void k_prep_w1(const float* __restrict__ Wc1,
                                                 uint4* __restrict__ w1f) {
  int t = blockIdx.x*256 + threadIdx.x;    // 8192 total
  int g = t >> 6, lane = t & 63;
  int q = g >> 5, kk = (g >> 3) & 3, mt = g & 7;
  int o = q*128 + mt*16 + (lane & 15);
  int kbase = kk*32 + (lane >> 4)*8;
  unsigned s[8];
  #pragma unroll
  for (int j = 0; j < 8; ++j) s[j] = f2bf(Wc1[(kbase+j)*512 + o]);
  uint4 u;
  u.x = s[0] | (s[1]<<16); u.y = s[2] | (s[3]<<16);
  u.z = s[4] | (s[5]<<16); u.w = s[6] | (s[7]<<16);
  w1f[g*64 + lane] = u;
}

// Wr6[6][512] = sym-folded (Wvo @ Wc1)
__global__ __launch_bounds__(256) void k_prep_wr6(const float* __restrict__ Wkv,
                                                  const float* __restrict__ Wc1,
                                                  float* __restrict__ Wr6) {
  int idx = blockIdx.x*256 + threadIdx.x;   // 3072
  if (idx >= 6*512) return;
  int d = idx >> 9, o = idx & 511;
  float s = 0.f;
  for (int k = 0; k < 128; ++k) {
    float w = Wkv[c_pa[d]*KV + 2*k + 1];
    if (d >= 3) w += Wkv[c_pb[d]*KV + 2*k + 1];
    s += w * Wc1[k*512 + o];
  }
  Wr6[d*512 + o] = s;
}

// ---------- counting sort(s): by row always, by col when FULL ----------
__global__ __launch_bounds__(256) void k_hist2(const int* __restrict__ row,
                                               const int* __restrict__ col,
                                               int* __restrict__ cr,
                                               int* __restrict__ cc, int E) {
  int e = blockIdx.x*256 + threadIdx.x;
  if (e >= E) return;
  atomicAdd(&cr[row[e]], 1);
  if (cc) atomicAdd(&cc[col[e]], 1);
}

// block 0 scans row-counts, block 1 (if launched) scans col-counts
__global__ __launch_bounds__(1024) void k_scan2(
    const int* __restrict__ cr, int* __restrict__ rstart, int* __restrict__ rcur,
    const int* __restrict__ cc, int* __restrict__ cstart, int* __restrict__ ccur,
    int n) {
  const int* counts = (blockIdx.x == 0) ? cr : cc;
  int* start = (blockIdx.x == 0) ? rstart : cstart;
  int* cursor = (blockIdx.x == 0) ? rcur : ccur;
  __shared__ int wsum[16];
  __shared__ int carry_s;
  const int tid = threadIdx.x, lane = tid & 63, wid = tid >> 6;
  if (tid == 0) carry_s = 0;
  __syncthreads();
  for (int base = 0; base < n; base += 1024) {
    int i = base + tid;
    int v = (i < n) ? counts[i] : 0;
    int s = v;
    #pragma unroll
    for (int off = 1; off < 64; off <<= 1) {
      int t = __shfl_up(s, off, 64);
      if (lane >= off) s += t;
    }
    if (lane == 63) wsum[wid] = s;
    __syncthreads();
    if (wid == 0 && lane < 16) {
      int w = wsum[lane];
      #pragma unroll
      for (int off = 1; off < 16; off <<= 1) {
        int t = __shfl_up(w, off, 16);
        if (lane >= off) w += t;
      }
      wsum[lane] = w;
    }
    __syncthreads();
    int wexcl = (wid == 0) ? 0 : wsum[wid-1];
    int excl = carry_s + wexcl + (s - v);
    if (i < n) { start[i] = excl; cursor[i] = excl; }
    __syncthreads();
    if (tid == 0) carry_s += wsum[15];
    __syncthreads();
  }
  if (threadIdx.x == 0) start[n] = carry_s;
}

__global__ __launch_bounds__(256) void k_scatter2(
    const int* __restrict__ row, const int* __restrict__ col,
    int* __restrict__ rcur, int* __restrict__ eidx,
    int* __restrict__ ccur, int* __restrict__ eidx2, int E) {
  int e = blockIdx.x*256 + threadIdx.x;
  if (e >= E) return;
  int pos = atomicAdd(&rcur[row[e]], 1);
  eidx[pos] = e;
  if (ccur) {
    int pos2 = atomicAdd(&ccur[col[e]], 1);
    eidx2[pos2] = e;
  }
}

// ---------- K1: qn/kn fp32, vn bf16; 8 nodes/block ----------
__global__ __launch_bounds__(384) void k_node_proj(
    const float* __restrict__ h, const float* __restrict__ Wq,
    const float* __restrict__ bq, const float* __restrict__ Wkv,
    const float* __restrict__ bkv, float* __restrict__ qn,
    float* __restrict__ kn, unsigned short* __restrict__ vn, int N)
{
  __shared__ float hs[8][H];
  const int n0 = blockIdx.x * 8;
  const int t = threadIdx.x;
  for (int idx = t; idx < 8*H; idx += 384) {
    int nn = idx >> 7, jj = idx & 127;
    hs[nn][jj] = (n0 + nn < N) ? h[(size_t)(n0+nn)*H + jj] : 0.f;
  }
  __syncthreads();
  float a[8] = {0.f,0.f,0.f,0.f,0.f,0.f,0.f,0.f};
  if (t < H) {
    #pragma unroll 4
    for (int j = 0; j < H; ++j) {
      float w = Wq[j*H + t];
      #pragma unroll
      for (int k = 0; k < 8; ++k) a[k] += hs[k][j]*w;
    }
    float b = bq[t];
    #pragma unroll
    for (int k = 0; k < 8; ++k)
      if (n0+k < N) qn[(size_t)(n0+k)*H + t] = a[k] + b;
  } else {
    int c = t - H;
    #pragma unroll 4
    for (int j = 0; j < H; ++j) {
      float w = Wkv[(9 + j)*KV + c];
      #pragma unroll
      for (int k = 0; k < 8; ++k) a[k] += hs[k][j]*w;
    }
    float b = bkv[c];
    size_t ch = (size_t)(c >> 1);
    if (c & 1) {
      #pragma unroll
      for (int k = 0; k < 8; ++k)
        if (n0+k < N) vn[(size_t)(n0+k)*H + ch] = f2bf(a[k] + b);
    } else {
      #pragma unroll
      for (int k = 0; k < 8; ++k)
        if (n0+k < N) kn[(size_t)(n0+k)*H + ch] = a[k] + b;
    }
  }
}

// ---------- K2: raw alpha per edge (CSR row order), optional rad6 stash ----------
__global__ __launch_bounds__(256) void k_edge_alpha(
    const float* __restrict__ coord, const int* __restrict__ row,
    const int* __restrict__ col, const float* __restrict__ Wkv,
    const int* __restrict__ eidx, const float* __restrict__ qn,
    const float* __restrict__ kn, float* __restrict__ aout,
    float4* __restrict__ rad6s, int E)
{
  __shared__ float wke6[6*128];    // sym-folded Wkv even cols
  const int tid = threadIdx.x;
  for (int idx = tid; idx < 6*128; idx += 256) {
    int d = idx >> 7, j = idx & 127;
    float w = Wkv[c_pa[d]*KV + 2*j];
    if (d >= 3) w += Wkv[c_pb[d]*KV + 2*j];
    wke6[idx] = w;
  }
  __syncthreads();
  int lane = tid & 63;
  int gw = (blockIdx.x * 256 + tid) >> 6;
  int nw = (gridDim.x * 256) >> 6;
  int chunk = (E + nw - 1) / nw;
  int j0 = gw*chunk, j1 = min(E, j0 + chunk);
  for (int j = j0; j < j1; ++j) {
    int e = eidx[j];               // row-sorted -> qn[r] L1 reuse
    int r = row[e], c = col[e];
    float cd[9], r6[6];
    #pragma unroll
    for (int i = 0; i < 9; ++i) cd[i] = coord[(size_t)r*9+i] - coord[(size_t)c*9+i];
    rad6_from_cd(cd, r6);
    float q0 = qn[(size_t)r*H + lane];
    float q1 = qn[(size_t)r*H + 64 + lane];
    float k0 = kn[(size_t)c*H + lane];
    float k1 = kn[(size_t)c*H + 64 + lane];
    #pragma unroll
    for (int p = 0; p < 6; ++p) {
      k0 += r6[p]*wke6[p*128 + lane];
      k1 += r6[p]*wke6[p*128 + 64 + lane];
    }
    float acc = q0*k0 + q1*k1;
    #pragma unroll
    for (int m = 32; m > 0; m >>= 1) acc += __shfl_xor(acc, m, 64);
    if (lane == 0) {
      aout[e] = acc;
      if (rad6s) {
        rad6s[(size_t)e*2]     = make_float4(r6[0], r6[1], r6[2], r6[3]);
        rad6s[(size_t)e*2 + 1] = make_float4(r6[4], r6[5], 0.f, 0.f);
      }
    }
  }
}

// ---------- K3: per-row softmax normalize ----------
__global__ __launch_bounds__(256) void k_row_softmax(
    const int* __restrict__ row_start, const int* __restrict__ eidx,
    float* __restrict__ aout, int N)
{
  int r = blockIdx.x*256 + threadIdx.x;
  if (r >= N) return;
  int js = row_start[r], je = row_start[r+1];
  if (js >= je) return;
  float m = -1e30f;
  for (int j = js; j < je; ++j) m = fmaxf(m, aout[eidx[j]]);
  float s = 0.f;
  for (int j = js; j < je; ++j) s += __expf(aout[eidx[j]] - m);
  float inv = 1.f / s;
  for (int j = js; j < je; ++j) {
    int ie = eidx[j];
    aout[ie] = __expf(aout[ie] - m) * inv;
  }
}

// ---------- K4a: hn[N][512] bf16 = vn @ Wc1 (node MFMA GEMM, verified R9) ----------
__global__ __launch_bounds__(256) void k_node_hn(
    const unsigned* __restrict__ vnu, const uint4* __restrict__ w1f,
    unsigned short* __restrict__ hn, int N)
{
  __shared__ unsigned vt[128*64];
  __shared__ unsigned short hno[128*128];
  const int tid = threadIdx.x;
  const int wid = tid >> 6, lane = tid & 63;
  const int quad = lane >> 4, colc = lane & 15;
  const int n0 = blockIdx.x * 128;
  for (int i = 0; i < 32; ++i) {
    int el = i*4 + wid;
    int c = n0 + el; if (c >= N) c = N - 1;
    unsigned pk = vnu[(size_t)c*64 + lane];
    vt[el*64 + (((lane>>2) ^ (el&15))<<2) + (lane&3)] = pk;
  }
  __syncthreads();
  const int ntbase = wid*32;
  for (int q = 0; q < 4; ++q) {
    f32x4 acc[8][2];
    #pragma unroll
    for (int mt = 0; mt < 8; ++mt)
      #pragma unroll
      for (int nt = 0; nt < 2; ++nt) acc[mt][nt] = (f32x4){0.f,0.f,0.f,0.f};
    #pragma unroll
    for (int kk = 0; kk < 4; ++kk) {
      FragU bfr[2];
      #pragma unroll
      for (int nt = 0; nt < 2; ++nt) {
        int rrow = ntbase + nt*16 + colc;
        int chunk = kk*4 + quad;
        bfr[nt].u = *((const uint4*)&vt[rrow*64 + ((chunk ^ (rrow&15))<<2)]);
      }
      #pragma unroll
      for (int mt = 0; mt < 8; ++mt) {
        FragU afr;
        afr.u = w1f[(((q*4+kk)*8+mt)<<6) + lane];
        #pragma unroll
        for (int nt = 0; nt < 2; ++nt)
          acc[mt][nt] = __builtin_amdgcn_mfma_f32_16x16x32_bf16(
              afr.s, bfr[nt].s, acc[mt][nt], 0, 0, 0);
      }
    }
    #pragma unroll
    for (int mt = 0; mt < 8; ++mt)
      #pragma unroll
      for (int nt = 0; nt < 2; ++nt) {
        int node = ntbase + nt*16 + colc;
        int o = mt*16 + quad*4;
        unsigned lo = (unsigned)f2bf(acc[mt][nt][0]) | ((unsigned)f2bf(acc[mt][nt][1]) << 16);
        unsigned hi = (unsigned)f2bf(acc[mt][nt][2]) | ((unsigned)f2bf(acc[mt][nt][3]) << 16);
        *((uint2*)&hno[node*128 + o]) = make_uint2(lo, hi);
      }
    __syncthreads();
    const uint4* hns = (const uint4*)hno;
    #pragma unroll
    for (int it = 0; it < 8; ++it) {
      int u = it*256 + tid;
      int node = u >> 4, within = u & 15;
      int gn = n0 + node;
      if (gn < N) ((uint4*)hn)[(size_t)gn*64 + q*16 + within] = hns[node*16 + within];
    }
    __syncthreads();
  }
}

// ---------- K4b: mlpout[e][3] = silu(hn[col] + rad6@Wr6) @ Wc2 ----------
// FULL: col-sorted order (hn L1 locality) + rad6 stash loads.
template<bool FULL>
__global__ __launch_bounds__(256) void k_edge_mlp2(
    const float* __restrict__ coord, const int* __restrict__ row,
    const int* __restrict__ col, const float* __restrict__ Wr6,
    const float* __restrict__ Wc2, const uint4* __restrict__ hn4,
    const int* __restrict__ eidx2, const float4* __restrict__ rad6s,
    float* __restrict__ mlpout, int E)
{
  const int tid = threadIdx.x, wid = tid >> 6, lane = tid & 63;
  float wr6[6][8], w2r[8][3];
  #pragma unroll
  for (int p = 0; p < 6; ++p)
    #pragma unroll
    for (int j = 0; j < 8; ++j) wr6[p][j] = Wr6[p*512 + lane*8 + j];
  #pragma unroll
  for (int j = 0; j < 8; ++j) {
    w2r[j][0] = Wc2[(lane*8+j)*3 + 0];
    w2r[j][1] = Wc2[(lane*8+j)*3 + 1];
    w2r[j][2] = Wc2[(lane*8+j)*3 + 2];
  }
  int gw = blockIdx.x*4 + wid;
  int nw = gridDim.x*4;
  int chunk = (E + nw - 1)/nw;
  int j0 = gw*chunk, j1 = min(E, j0 + chunk);
  for (int j = j0; j < j1; ++j) {
    int e = FULL ? eidx2[j] : j;
    int c = col[e];
    uint4 hh = hn4[(size_t)c*64 + lane];
    float r6[6];
    if (FULL) {
      float4 s1 = rad6s[(size_t)e*2];
      float4 s2 = rad6s[(size_t)e*2 + 1];
      r6[0]=s1.x; r6[1]=s1.y; r6[2]=s1.z; r6[3]=s1.w; r6[4]=s2.x; r6[5]=s2.y;
    } else {
      int r = row[e];
      float cd[9];
      #pragma unroll
      for (int i = 0; i < 9; ++i) cd[i] = coord[(size_t)r*9+i] - coord[(size_t)c*9+i];
      rad6_from_cd(cd, r6);
    }
    unsigned uu[4] = {hh.x, hh.y, hh.z, hh.w};
    float cv0 = 0.f, cv1 = 0.f, cv2 = 0.f;
    #pragma unroll
    for (int d = 0; d < 4; ++d) {
      float s0 = __uint_as_float(uu[d] << 16);
      float s1 = __uint_as_float(uu[d] & 0xffff0000u);
      int ja = d*2, jb = d*2 + 1;
      #pragma unroll
      for (int p = 0; p < 6; ++p) {
        s0 += r6[p]*wr6[p][ja];
        s1 += r6[p]*wr6[p][jb];
      }
      s0 = s0 / (1.f + __expf(-s0));
      s1 = s1 / (1.f + __expf(-s1));
      cv0 += s0*w2r[ja][0] + s1*w2r[jb][0];
      cv1 += s0*w2r[ja][1] + s1*w2r[jb][1];
      cv2 += s0*w2r[ja][2] + s1*w2r[jb][2];
    }
    #pragma unroll
    for (int m = 32; m > 0; m >>= 1) {
      cv0 += __shfl_xor(cv0, m, 64);
      cv1 += __shfl_xor(cv1, m, 64);
      cv2 += __shfl_xor(cv2, m, 64);
    }
    if (lane == 0) {
      float* mp = &mlpout[(size_t)e*3];
      mp[0] = cv0; mp[1] = cv1; mp[2] = cv2;
    }
  }
}

// ---------- K5: per-row h_out AND coord_out (CSR, t6 fold) ----------
__global__ __launch_bounds__(256) void k_row_final(
    const float* __restrict__ h, const float* __restrict__ coord,
    const int* __restrict__ col, const float* __restrict__ Wkv,
    const int* __restrict__ row_start, const int* __restrict__ eidx,
    const float* __restrict__ aout, const unsigned* __restrict__ vnu,
    const float* __restrict__ mlpout, float* __restrict__ hout,
    float* __restrict__ cout, int N)
{
  __shared__ float wvo6[6*128];    // sym-folded Wkv odd cols
  const int tid = threadIdx.x;
  for (int idx = tid; idx < 6*128; idx += 256) {
    int d = idx >> 7, j = idx & 127;
    float w = Wkv[c_pa[d]*KV + 2*j + 1];
    if (d >= 3) w += Wkv[c_pb[d]*KV + 2*j + 1];
    wvo6[idx] = w;
  }
  __syncthreads();
  const int wid = tid >> 6, lane = tid & 63;
  const int r = blockIdx.x*4 + wid;
  if (r >= N) return;
  int js = row_start[r], je = row_start[r+1];
  float cr[9];
  #pragma unroll
  for (int i = 0; i < 9; ++i) cr[i] = coord[(size_t)r*9 + i];
  float acc0 = 0.f, acc1 = 0.f;
  float t6[6], cg[9];
  #pragma unroll
  for (int p = 0; p < 6; ++p) t6[p] = 0.f;
  #pragma unroll
  for (int p = 0; p < 9; ++p) cg[p] = 0.f;
  for (int j = js; j < je; j += 2) {
    int ie0 = eidx[j];
    bool has1 = (j + 1 < je);
    int ie1 = has1 ? eidx[j+1] : ie0;
    int c0 = col[ie0], c1 = col[ie1];
    float a0 = aout[ie0];
    float a1 = has1 ? aout[ie1] : 0.f;
    unsigned v0 = vnu[(size_t)c0*64 + lane];
    unsigned v1 = vnu[(size_t)c1*64 + lane];
    float m00 = mlpout[(size_t)ie0*3+0], m01 = mlpout[(size_t)ie0*3+1], m02 = mlpout[(size_t)ie0*3+2];
    float m10 = mlpout[(size_t)ie1*3+0], m11 = mlpout[(size_t)ie1*3+1], m12 = mlpout[(size_t)ie1*3+2];
    float cd0[9], cd1[9], r60[6], r61[6];
    #pragma unroll
    for (int i = 0; i < 9; ++i) {
      cd0[i] = cr[i] - coord[(size_t)c0*9+i];
      cd1[i] = cr[i] - coord[(size_t)c1*9+i];
    }
    rad6_from_cd(cd0, r60);
    rad6_from_cd(cd1, r61);
    #pragma unroll
    for (int p = 0; p < 6; ++p) t6[p] += a0*r60[p] + a1*r61[p];
    acc0 += a0*__uint_as_float(v0 << 16)         + a1*__uint_as_float(v1 << 16);
    acc1 += a0*__uint_as_float(v0 & 0xffff0000u) + a1*__uint_as_float(v1 & 0xffff0000u);
    float p00 = a0*m00, p01 = a0*m01, p02 = a0*m02;
    float p10 = a1*m10, p11 = a1*m11, p12 = a1*m12;
    #pragma unroll
    for (int d = 0; d < 3; ++d) {
      cg[0+d] += p00*cd0[0+d] + p10*cd1[0+d];
      cg[3+d] += p01*cd0[3+d] + p11*cd1[3+d];
      cg[6+d] += p02*cd0[6+d] + p12*cd1[6+d];
    }
  }
  #pragma unroll
  for (int p = 0; p < 6; ++p) {
    acc0 += t6[p] * wvo6[p*128 + 2*lane];
    acc1 += t6[p] * wvo6[p*128 + 2*lane + 1];
  }
  hout[(size_t)r*H + 2*lane]     = h[(size_t)r*H + 2*lane]     + acc0;
  hout[(size_t)r*H + 2*lane + 1] = h[(size_t)r*H + 2*lane + 1] + acc1;
  if (lane == 0) {
    #pragma unroll
    for (int i = 0; i < 9; ++i) {
      float x = fminf(10.f, fmaxf(-10.f, cg[i]));
      cout[(size_t)r*9 + i] = cr[i] + x;
    }
  }
}

extern "C" void kernel_launch(void* const* d_in, const int* in_sizes, int n_in,
                              void* d_out, int out_size, void* d_ws, size_t ws_size,
                              hipStream_t stream)
{
  const float* h     = (const float*)d_in[0];
  const float* coord = (const float*)d_in[1];
  const int* row = (const int*)d_in[2];
  const int* col = (const int*)d_in[3];
  const float* Wq  = (const float*)d_in[4];
  const float* bq  = (const float*)d_in[5];
  const float* Wkv = (const float*)d_in[6];
  const float* bkv = (const float*)d_in[7];
  const float* Wc1 = (const float*)d_in[8];
  const float* Wc2 = (const float*)d_in[9];
  const int N = in_sizes[0] / H;
  const int E = in_sizes[2];
  float* out = (float*)d_out;

  // base layout (round-9-equivalent): [qn|kn fp32] <- hn bf16 aliases after alpha
  char* p = (char*)d_ws;
  float* qn = (float*)p;
  float* kn = (float*)(p + (size_t)N*H*4);
  unsigned short* hn = (unsigned short*)p;
  p += (size_t)N*H*8;
  unsigned short* vn = (unsigned short*)p;  p += (size_t)N*H*2;
  float* mlpout = (float*)p;                p += (size_t)E*3*4;
  int* counts_r = (int*)p;                  p += (size_t)N*4;
  int* row_start = (int*)p;                 p += (size_t)(N+1)*4;
  int* cursor_r = (int*)p;                  p += (size_t)N*4;
  int* eidx = (int*)p;                      p += (size_t)E*4;
  uint4* w1f = (uint4*)((((size_t)p) + 15) & ~(size_t)15);
  float* Wr6 = (float*)((char*)w1f + 8192*16);
  char* q = (char*)Wr6 + 6*512*4;
  const size_t need_base = (size_t)(q - (char*)d_ws);
  // FULL extras: col sort + rad6 stash
  int* counts_c = (int*)q;                  q += (size_t)N*4;
  int* cstart = (int*)q;                    q += (size_t)(N+1)*4;
  int* cursor_c = (int*)q;                  q += (size_t)N*4;
  int* eidx2 = (int*)q;                     q += (size_t)E*4;
  float4* rad6s = (float4*)((((size_t)q) + 15) & ~(size_t)15);
  const size_t need_full = (size_t)((char*)rad6s + (size_t)E*32 - (char*)d_ws);

  if (ws_size < need_base) {
    k_sentinel<<<(out_size + 255)/256, 256, 0, stream>>>(out, out_size);
    return;
  }
  const bool FULL = (ws_size >= need_full);

  float* hout = out;
  float* cout = out + (size_t)N*H;
  float* aout = cout + (size_t)N*9;   // normalized alpha (edge order)

  k_zero<<<(N + 255)/256, 256, 0, stream>>>((float*)counts_r, N);
  if (FULL) k_zero<<<(N + 255)/256, 256, 0, stream>>>((float*)counts_c, N);
  k_prep_w1<<<32, 256, 0, stream>>>(Wc1, w1f);
  k_prep_wr6<<<12, 256, 0, stream>>>(Wkv, Wc1, Wr6);
  k_hist2<<<(E + 255)/256, 256, 0, stream>>>(row, col, counts_r,
                                             FULL ? counts_c : nullptr, E);
  k_node_proj<<<(N + 7)/8, 384, 0, stream>>>(h, Wq, bq, Wkv, bkv, qn, kn, vn, N);
  k_scan2<<<FULL ? 2 : 1, 1024, 0, stream>>>(counts_r, row_start, cursor_r,
                                             counts_c, cstart, cursor_c, N);
  k_scatter2<<<(E + 255)/256, 256, 0, stream>>>(row, col, cursor_r, eidx,
                                                FULL ? cursor_c : nullptr,
                                                FULL ? eidx2 : nullptr, E);
  k_edge_alpha<<<1024, 256, 0, stream>>>(coord, row, col, Wkv, eidx, qn, kn, aout,
                                         FULL ? rad6s : nullptr, E);
  k_row_softmax<<<(N + 255)/256, 256, 0, stream>>>(row_start, eidx, aout, N);
  // qn/kn dead from here: hn overwrites their region
  k_node_hn<<<(N + 127)/128, 256, 0, stream>>>((const unsigned*)vn, w1f, hn, N);
  if (FULL)
    k_edge_mlp2<true><<<2048, 256, 0, stream>>>(coord, row, col, Wr6, Wc2,
        (const uint4*)hn, eidx2, rad6s, mlpout, E);
  else
    k_edge_mlp2<false><<<2048, 256, 0, stream>>>(coord, row, col, Wr6, Wc2,
        (const uint4*)hn, nullptr, nullptr, mlpout, E);
  k_row_final<<<(N + 3)/4, 256, 0, stream>>>(h, coord, col, Wkv, row_start, eidx,
                                             aout, (const unsigned*)vn, mlpout,
                                             hout, cout, N);
}

// Round 11
// 923.781 us; speedup vs baseline: 1.1223x; 1.1223x over previous
//
#include <hip/hip_runtime.h>

#define H 128
#define KV 256

typedef short bf16x8 __attribute__((ext_vector_type(8)));
typedef float f32x4 __attribute__((ext_vector_type(4)));
union FragU { uint4 u; bf16x8 s; };

__device__ __forceinline__ float bf2f(unsigned short u) {
  return __uint_as_float(((unsigned)u) << 16);
}
__device__ __forceinline__ unsigned short f2bf(float f) {
  unsigned b = __float_as_uint(f);
  b += 0x7FFFu + ((b >> 16) & 1u);   // round-to-nearest-even
  return (unsigned short)(b >> 16);
}
// rad6 = unique entries of the symmetric radial matrix [00,11,22,01,02,12]
__device__ __forceinline__ void rad6_from_cd(const float cd[9], float r6[6]) {
  r6[0] = cd[0]*cd[0] + cd[1]*cd[1] + cd[2]*cd[2];
  r6[1] = cd[3]*cd[3] + cd[4]*cd[4] + cd[5]*cd[5];
  r6[2] = cd[6]*cd[6] + cd[7]*cd[7] + cd[8]*cd[8];
  r6[3] = cd[0]*cd[3] + cd[1]*cd[4] + cd[2]*cd[5];
  r6[4] = cd[0]*cd[6] + cd[1]*cd[7] + cd[2]*cd[8];
  r6[5] = cd[3]*cd[6] + cd[4]*cd[7] + cd[5]*cd[8];
}
__constant__ int c_pa[6] = {0,4,8,1,2,5};
__constant__ int c_pb[6] = {0,0,0,3,6,7};

__global__ __launch_bounds__(256) void k_zero(float* __restrict__ p, int n) {
  int i = blockIdx.x * 256 + threadIdx.x;
  if (i < n) p[i] = 0.f;
}
__global__ __launch_bounds__(256) void k_sentinel(float* __restrict__ out, int n) {
  int i = blockIdx.x * 256 + threadIdx.x;
  if (i < n) out[i] = 1000.0f;
}

// pack Wc1 (128x512 fp32) into bf16 fragment order (verified R5-R10)
__global__ __launch_bounds__(256) void k_prep_w1(const float* __restrict__ Wc1,
                                                 uint4* __restrict__ w1f) {
  int t = blockIdx.x*256 + threadIdx.x;    // 8192 total
  int g = t >> 6, lane = t & 63;
  int q = g >> 5, kk = (g >> 3) & 3, mt = g & 7;
  int o = q*128 + mt*16 + (lane & 15);
  int kbase = kk*32 + (lane >> 4)*8;
  unsigned s[8];
  #pragma unroll
  for (int j = 0; j < 8; ++j) s[j] = f2bf(Wc1[(kbase+j)*512 + o]);
  uint4 u;
  u.x = s[0] | (s[1]<<16); u.y = s[2] | (s[3]<<16);
  u.z = s[4] | (s[5]<<16); u.w = s[6] | (s[7]<<16);
  w1f[g*64 + lane] = u;
}

// Wr6[6][512] = sym-folded (Wvo @ Wc1)
__global__ __launch_bounds__(256) void k_prep_wr6(const float* __restrict__ Wkv,
                                                  const float* __restrict__ Wc1,
                                                  float* __restrict__ Wr6) {
  int idx = blockIdx.x*256 + threadIdx.x;   // 3072
  if (idx >= 6*512) return;
  int d = idx >> 9, o = idx & 511;
  float s = 0.f;
  for (int k = 0; k < 128; ++k) {
    float w = Wkv[c_pa[d]*KV + 2*k + 1];
    if (d >= 3) w += Wkv[c_pb[d]*KV + 2*k + 1];
    s += w * Wc1[k*512 + o];
  }
  Wr6[d*512 + o] = s;
}

// ---------- dual counting sort (row + col) ----------
__global__ __launch_bounds__(256) void k_hist2(const int* __restrict__ row,
                                               const int* __restrict__ col,
                                               int* __restrict__ cr,
                                               int* __restrict__ cc, int E) {
  int e = blockIdx.x*256 + threadIdx.x;
  if (e >= E) return;
  atomicAdd(&cr[row[e]], 1);
  atomicAdd(&cc[col[e]], 1);
}

__global__ __launch_bounds__(1024) void k_scan2(
    const int* __restrict__ cr, int* __restrict__ rstart, int* __restrict__ rcur,
    const int* __restrict__ cc, int* __restrict__ cstart, int* __restrict__ ccur,
    int n) {
  const int* counts = (blockIdx.x == 0) ? cr : cc;
  int* start = (blockIdx.x == 0) ? rstart : cstart;
  int* cursor = (blockIdx.x == 0) ? rcur : ccur;
  __shared__ int wsum[16];
  __shared__ int carry_s;
  const int tid = threadIdx.x, lane = tid & 63, wid = tid >> 6;
  if (tid == 0) carry_s = 0;
  __syncthreads();
  for (int base = 0; base < n; base += 1024) {
    int i = base + tid;
    int v = (i < n) ? counts[i] : 0;
    int s = v;
    #pragma unroll
    for (int off = 1; off < 64; off <<= 1) {
      int t = __shfl_up(s, off, 64);
      if (lane >= off) s += t;
    }
    if (lane == 63) wsum[wid] = s;
    __syncthreads();
    if (wid == 0 && lane < 16) {
      int w = wsum[lane];
      #pragma unroll
      for (int off = 1; off < 16; off <<= 1) {
        int t = __shfl_up(w, off, 16);
        if (lane >= off) w += t;
      }
      wsum[lane] = w;
    }
    __syncthreads();
    int wexcl = (wid == 0) ? 0 : wsum[wid-1];
    int excl = carry_s + wexcl + (s - v);
    if (i < n) { start[i] = excl; cursor[i] = excl; }
    __syncthreads();
    if (tid == 0) carry_s += wsum[15];
    __syncthreads();
  }
  if (threadIdx.x == 0) start[n] = carry_s;
}

__global__ __launch_bounds__(256) void k_scatter2(
    const int* __restrict__ row, const int* __restrict__ col,
    int* __restrict__ rcur, int* __restrict__ eidx,
    int* __restrict__ ccur, int* __restrict__ eidx2, int E) {
  int e = blockIdx.x*256 + threadIdx.x;
  if (e >= E) return;
  int pos = atomicAdd(&rcur[row[e]], 1);
  eidx[pos] = e;
  int pos2 = atomicAdd(&ccur[col[e]], 1);
  eidx2[pos2] = e;
}

// ---------- K1: qn/kn fp32, vn bf16; 8 nodes/block ----------
__global__ __launch_bounds__(384) void k_node_proj(
    const float* __restrict__ h, const float* __restrict__ Wq,
    const float* __restrict__ bq, const float* __restrict__ Wkv,
    const float* __restrict__ bkv, float* __restrict__ qn,
    float* __restrict__ kn, unsigned short* __restrict__ vn, int N)
{
  __shared__ float hs[8][H];
  const int n0 = blockIdx.x * 8;
  const int t = threadIdx.x;
  for (int idx = t; idx < 8*H; idx += 384) {
    int nn = idx >> 7, jj = idx & 127;
    hs[nn][jj] = (n0 + nn < N) ? h[(size_t)(n0+nn)*H + jj] : 0.f;
  }
  __syncthreads();
  float a[8] = {0.f,0.f,0.f,0.f,0.f,0.f,0.f,0.f};
  if (t < H) {
    #pragma unroll 4
    for (int j = 0; j < H; ++j) {
      float w = Wq[j*H + t];
      #pragma unroll
      for (int k = 0; k < 8; ++k) a[k] += hs[k][j]*w;
    }
    float b = bq[t];
    #pragma unroll
    for (int k = 0; k < 8; ++k)
      if (n0+k < N) qn[(size_t)(n0+k)*H + t] = a[k] + b;
  } else {
    int c = t - H;
    #pragma unroll 4
    for (int j = 0; j < H; ++j) {
      float w = Wkv[(9 + j)*KV + c];
      #pragma unroll
      for (int k = 0; k < 8; ++k) a[k] += hs[k][j]*w;
    }
    float b = bkv[c];
    size_t ch = (size_t)(c >> 1);
    if (c & 1) {
      #pragma unroll
      for (int k = 0; k < 8; ++k)
        if (n0+k < N) vn[(size_t)(n0+k)*H + ch] = f2bf(a[k] + b);
    } else {
      #pragma unroll
      for (int k = 0; k < 8; ++k)
        if (n0+k < N) kn[(size_t)(n0+k)*H + ch] = a[k] + b;
    }
  }
}

// ---------- K2: fused per-row alpha + online softmax + h_out ----------
// qw trick: q.(rad@Wke) = rad6 . (q@Wke6^T)  (per-row 6-vector).
// One pass per edge: kn/vn/coord gathers once; flash-style m,l with rescaled
// acc/t6; araw in LDS (deg<=64 fast path) else spilled raw to aout + fixup.
__global__ __launch_bounds__(256) void k_row_fused(
    const float* __restrict__ h, const float* __restrict__ coord,
    const int* __restrict__ col, const float* __restrict__ Wkv,
    const int* __restrict__ row_start, const int* __restrict__ eidx,
    const float* __restrict__ qn, const float* __restrict__ kn,
    const unsigned* __restrict__ vnu, float* __restrict__ aout,
    float* __restrict__ hout, int N)
{
  __shared__ float wke6[6*128];
  __shared__ float wvo6[6*128];
  __shared__ float araw[4][64];
  const int tid = threadIdx.x;
  for (int idx = tid; idx < 6*128; idx += 256) {
    int d = idx >> 7, j = idx & 127;
    float we = Wkv[c_pa[d]*KV + 2*j];
    float wo = Wkv[c_pa[d]*KV + 2*j + 1];
    if (d >= 3) { we += Wkv[c_pb[d]*KV + 2*j]; wo += Wkv[c_pb[d]*KV + 2*j + 1]; }
    wke6[idx] = we; wvo6[idx] = wo;
  }
  __syncthreads();
  const int wid = tid >> 6, lane = tid & 63;
  const int r = blockIdx.x*4 + wid;
  if (r >= N) return;
  const int js = row_start[r], je = row_start[r+1];
  const int deg = je - js;
  float q0 = qn[(size_t)r*H + lane];
  float q1 = qn[(size_t)r*H + 64 + lane];
  float qw[6];
  #pragma unroll
  for (int d = 0; d < 6; ++d) {
    float p = q0*wke6[d*128 + lane] + q1*wke6[d*128 + 64 + lane];
    #pragma unroll
    for (int m = 32; m > 0; m >>= 1) p += __shfl_xor(p, m, 64);
    qw[d] = p;
  }
  float cr[9];
  #pragma unroll
  for (int i = 0; i < 9; ++i) cr[i] = coord[(size_t)r*9 + i];

  float m = -1e30f, l = 0.f, acc0 = 0.f, acc1 = 0.f;
  float t6[6] = {0.f,0.f,0.f,0.f,0.f,0.f};
  const bool big = (deg > 64);
  for (int base = js; base < je; base += 64) {
    int cnt = min(64, je - base);
    for (int t = 0; t < cnt; ++t) {
      int e = eidx[base + t];
      int c = col[e];
      float k0 = kn[(size_t)c*H + lane];
      float k1 = kn[(size_t)c*H + 64 + lane];
      unsigned v = vnu[(size_t)c*64 + lane];
      float cd[9], r6[6];
      #pragma unroll
      for (int i = 0; i < 9; ++i) cd[i] = cr[i] - coord[(size_t)c*9 + i];
      rad6_from_cd(cd, r6);
      float dot = q0*k0 + q1*k1;
      #pragma unroll
      for (int mm = 32; mm > 0; mm >>= 1) dot += __shfl_xor(dot, mm, 64);
      float ar = dot;
      #pragma unroll
      for (int d = 0; d < 6; ++d) ar += r6[d]*qw[d];
      float mn = fmaxf(m, ar);
      float scale = __expf(m - mn);    // first edge: exp(-huge)=0, accs are 0
      float w = __expf(ar - mn);
      l = l*scale + w;
      acc0 = acc0*scale + w*__uint_as_float(v << 16);
      acc1 = acc1*scale + w*__uint_as_float(v & 0xffff0000u);
      #pragma unroll
      for (int d = 0; d < 6; ++d) t6[d] = t6[d]*scale + w*r6[d];
      m = mn;
      if (lane == 0) araw[wid][t] = ar;
    }
    if (big && lane < cnt) aout[eidx[base + lane]] = araw[wid][lane];  // raw spill
  }
  float invl = (deg > 0) ? 1.f/l : 0.f;
  float o0 = acc0, o1 = acc1;
  #pragma unroll
  for (int d = 0; d < 6; ++d) {
    o0 += t6[d]*wvo6[d*128 + 2*lane];
    o1 += t6[d]*wvo6[d*128 + 2*lane + 1];
  }
  hout[(size_t)r*H + 2*lane]     = h[(size_t)r*H + 2*lane]     + o0*invl;
  hout[(size_t)r*H + 2*lane + 1] = h[(size_t)r*H + 2*lane + 1] + o1*invl;
  if (!big) {
    if (lane < deg) aout[eidx[js + lane]] = __expf(araw[wid][lane] - m)*invl;
  } else {
    for (int j = js + lane; j < je; j += 64) {
      int e = eidx[j];
      aout[e] = __expf(aout[e] - m)*invl;
    }
  }
}

// ---------- K4a: hn[N][512] bf16 = vn @ Wc1 (node MFMA GEMM, verified R9/R10) ----------
__global__ __launch_bounds__(256) void k_node_hn(
    const unsigned* __restrict__ vnu, const uint4* __restrict__ w1f,
    unsigned short* __restrict__ hn, int N)
{
  __shared__ unsigned vt[128*64];
  __shared__ unsigned short hno[128*128];
  const int tid = threadIdx.x;
  const int wid = tid >> 6, lane = tid & 63;
  const int quad = lane >> 4, colc = lane & 15;
  const int n0 = blockIdx.x * 128;
  for (int i = 0; i < 32; ++i) {
    int el = i*4 + wid;
    int c = n0 + el; if (c >= N) c = N - 1;
    unsigned pk = vnu[(size_t)c*64 + lane];
    vt[el*64 + (((lane>>2) ^ (el&15))<<2) + (lane&3)] = pk;
  }
  __syncthreads();
  const int ntbase = wid*32;
  for (int q = 0; q < 4; ++q) {
    f32x4 acc[8][2];
    #pragma unroll
    for (int mt = 0; mt < 8; ++mt)
      #pragma unroll
      for (int nt = 0; nt < 2; ++nt) acc[mt][nt] = (f32x4){0.f,0.f,0.f,0.f};
    #pragma unroll
    for (int kk = 0; kk < 4; ++kk) {
      FragU bfr[2];
      #pragma unroll
      for (int nt = 0; nt < 2; ++nt) {
        int rrow = ntbase + nt*16 + colc;
        int chunk = kk*4 + quad;
        bfr[nt].u = *((const uint4*)&vt[rrow*64 + ((chunk ^ (rrow&15))<<2)]);
      }
      #pragma unroll
      for (int mt = 0; mt < 8; ++mt) {
        FragU afr;
        afr.u = w1f[(((q*4+kk)*8+mt)<<6) + lane];
        #pragma unroll
        for (int nt = 0; nt < 2; ++nt)
          acc[mt][nt] = __builtin_amdgcn_mfma_f32_16x16x32_bf16(
              afr.s, bfr[nt].s, acc[mt][nt], 0, 0, 0);
      }
    }
    #pragma unroll
    for (int mt = 0; mt < 8; ++mt)
      #pragma unroll
      for (int nt = 0; nt < 2; ++nt) {
        int node = ntbase + nt*16 + colc;
        int o = mt*16 + quad*4;
        unsigned lo = (unsigned)f2bf(acc[mt][nt][0]) | ((unsigned)f2bf(acc[mt][nt][1]) << 16);
        unsigned hi = (unsigned)f2bf(acc[mt][nt][2]) | ((unsigned)f2bf(acc[mt][nt][3]) << 16);
        *((uint2*)&hno[node*128 + o]) = make_uint2(lo, hi);
      }
    __syncthreads();
    const uint4* hns = (const uint4*)hno;
    #pragma unroll
    for (int it = 0; it < 8; ++it) {
      int u = it*256 + tid;
      int node = u >> 4, within = u & 15;
      int gn = n0 + node;
      if (gn < N) ((uint4*)hn)[(size_t)gn*64 + q*16 + within] = hns[node*16 + within];
    }
    __syncthreads();
  }
}

// ---------- K4b: mlpout[e][3] = silu(hn[col] + rad6@Wr6) @ Wc2 ----------
// col-sorted order (hn L1 locality), rad6 inline.
__global__ __launch_bounds__(256) void k_edge_mlp2(
    const float* __restrict__ coord, const int* __restrict__ row,
    const int* __restrict__ col, const float* __restrict__ Wr6,
    const float* __restrict__ Wc2, const uint4* __restrict__ hn4,
    const int* __restrict__ eidx2, float* __restrict__ mlpout, int E)
{
  const int tid = threadIdx.x, wid = tid >> 6, lane = tid & 63;
  float wr6[6][8], w2r[8][3];
  #pragma unroll
  for (int p = 0; p < 6; ++p)
    #pragma unroll
    for (int j = 0; j < 8; ++j) wr6[p][j] = Wr6[p*512 + lane*8 + j];
  #pragma unroll
  for (int j = 0; j < 8; ++j) {
    w2r[j][0] = Wc2[(lane*8+j)*3 + 0];
    w2r[j][1] = Wc2[(lane*8+j)*3 + 1];
    w2r[j][2] = Wc2[(lane*8+j)*3 + 2];
  }
  int gw = blockIdx.x*4 + wid;
  int nw = gridDim.x*4;
  int chunk = (E + nw - 1)/nw;
  int j0 = gw*chunk, j1 = min(E, j0 + chunk);
  for (int j = j0; j < j1; ++j) {
    int e = eidx2[j];
    int c = col[e];
    int r = row[e];
    uint4 hh = hn4[(size_t)c*64 + lane];
    float cd[9], r6[6];
    #pragma unroll
    for (int i = 0; i < 9; ++i) cd[i] = coord[(size_t)r*9+i] - coord[(size_t)c*9+i];
    rad6_from_cd(cd, r6);
    unsigned uu[4] = {hh.x, hh.y, hh.z, hh.w};
    float cv0 = 0.f, cv1 = 0.f, cv2 = 0.f;
    #pragma unroll
    for (int d = 0; d < 4; ++d) {
      float s0 = __uint_as_float(uu[d] << 16);
      float s1 = __uint_as_float(uu[d] & 0xffff0000u);
      int ja = d*2, jb = d*2 + 1;
      #pragma unroll
      for (int p = 0; p < 6; ++p) {
        s0 += r6[p]*wr6[p][ja];
        s1 += r6[p]*wr6[p][jb];
      }
      s0 = s0 / (1.f + __expf(-s0));
      s1 = s1 / (1.f + __expf(-s1));
      cv0 += s0*w2r[ja][0] + s1*w2r[jb][0];
      cv1 += s0*w2r[ja][1] + s1*w2r[jb][1];
      cv2 += s0*w2r[ja][2] + s1*w2r[jb][2];
    }
    #pragma unroll
    for (int m = 32; m > 0; m >>= 1) {
      cv0 += __shfl_xor(cv0, m, 64);
      cv1 += __shfl_xor(cv1, m, 64);
      cv2 += __shfl_xor(cv2, m, 64);
    }
    if (lane == 0) {
      float* mp = &mlpout[(size_t)e*3];
      mp[0] = cv0; mp[1] = cv1; mp[2] = cv2;
    }
  }
}

// ---------- K5: coord_out (wave per row, lane per edge) ----------
__global__ __launch_bounds__(256) void k_coord(
    const float* __restrict__ coord, const int* __restrict__ col,
    const int* __restrict__ row_start, const int* __restrict__ eidx,
    const float* __restrict__ aout, const float* __restrict__ mlpout,
    float* __restrict__ cout, int N)
{
  const int tid = threadIdx.x;
  const int wid = tid >> 6, lane = tid & 63;
  const int r = blockIdx.x*4 + wid;
  if (r >= N) return;
  const int js = row_start[r], je = row_start[r+1];
  float cr[9];
  #pragma unroll
  for (int i = 0; i < 9; ++i) cr[i] = coord[(size_t)r*9 + i];
  float cg[9] = {0.f,0.f,0.f,0.f,0.f,0.f,0.f,0.f,0.f};
  for (int j = js + lane; j < je; j += 64) {
    int e = eidx[j];
    float a = aout[e];
    int c = col[e];
    float cd[9];
    #pragma unroll
    for (int i = 0; i < 9; ++i) cd[i] = cr[i] - coord[(size_t)c*9 + i];
    float p0 = a*mlpout[(size_t)e*3+0];
    float p1 = a*mlpout[(size_t)e*3+1];
    float p2 = a*mlpout[(size_t)e*3+2];
    #pragma unroll
    for (int d = 0; d < 3; ++d) {
      cg[0+d] += p0*cd[0+d];
      cg[3+d] += p1*cd[3+d];
      cg[6+d] += p2*cd[6+d];
    }
  }
  #pragma unroll
  for (int i = 0; i < 9; ++i)
    #pragma unroll
    for (int m = 32; m > 0; m >>= 1) cg[i] += __shfl_xor(cg[i], m, 64);
  if (lane == 0) {
    #pragma unroll
    for (int i = 0; i < 9; ++i) {
      float x = fminf(10.f, fmaxf(-10.f, cg[i]));
      cout[(size_t)r*9 + i] = cr[i] + x;
    }
  }
}

extern "C" void kernel_launch(void* const* d_in, const int* in_sizes, int n_in,
                              void* d_out, int out_size, void* d_ws, size_t ws_size,
                              hipStream_t stream)
{
  const float* h     = (const float*)d_in[0];
  const float* coord = (const float*)d_in[1];
  const int* row = (const int*)d_in[2];
  const int* col = (const int*)d_in[3];
  const float* Wq  = (const float*)d_in[4];
  const float* bq  = (const float*)d_in[5];
  const float* Wkv = (const float*)d_in[6];
  const float* bkv = (const float*)d_in[7];
  const float* Wc1 = (const float*)d_in[8];
  const float* Wc2 = (const float*)d_in[9];
  const int N = in_sizes[0] / H;
  const int E = in_sizes[2];
  float* out = (float*)d_out;

  // layout: [qn|kn fp32] (dead after k_row_fused) <- hn bf16 aliases
  char* p = (char*)d_ws;
  float* qn = (float*)p;
  float* kn = (float*)(p + (size_t)N*H*4);
  unsigned short* hn = (unsigned short*)p;
  p += (size_t)N*H*8;
  unsigned short* vn = (unsigned short*)p;  p += (size_t)N*H*2;
  float* mlpout = (float*)p;                p += (size_t)E*3*4;
  int* counts_r = (int*)p;                  p += (size_t)N*4;
  int* counts_c = (int*)p;                  p += (size_t)N*4;   // adjacent: one zero
  int* row_start = (int*)p;                 p += (size_t)(N+1)*4;
  int* cursor_r = (int*)p;                  p += (size_t)N*4;
  int* cstart = (int*)p;                    p += (size_t)(N+1)*4;
  int* cursor_c = (int*)p;                  p += (size_t)N*4;
  int* eidx = (int*)p;                      p += (size_t)E*4;
  int* eidx2 = (int*)p;                     p += (size_t)E*4;
  uint4* w1f = (uint4*)((((size_t)p) + 15) & ~(size_t)15);
  float* Wr6 = (float*)((char*)w1f + 8192*16);
  const size_t need = (size_t)((char*)Wr6 + 6*512*4 - (char*)d_ws);

  if (ws_size < need) {
    k_sentinel<<<(out_size + 255)/256, 256, 0, stream>>>(out, out_size);
    return;
  }

  float* hout = out;
  float* cout = out + (size_t)N*H;
  float* aout = cout + (size_t)N*9;   // normalized alpha (edge order)

  k_zero<<<(2*N + 255)/256, 256, 0, stream>>>((float*)counts_r, 2*N);
  k_prep_w1<<<32, 256, 0, stream>>>(Wc1, w1f);
  k_prep_wr6<<<12, 256, 0, stream>>>(Wkv, Wc1, Wr6);
  k_hist2<<<(E + 255)/256, 256, 0, stream>>>(row, col, counts_r, counts_c, E);
  k_node_proj<<<(N + 7)/8, 384, 0, stream>>>(h, Wq, bq, Wkv, bkv, qn, kn, vn, N);
  k_scan2<<<2, 1024, 0, stream>>>(counts_r, row_start, cursor_r,
                                  counts_c, cstart, cursor_c, N);
  k_scatter2<<<(E + 255)/256, 256, 0, stream>>>(row, col, cursor_r, eidx,
                                                cursor_c, eidx2, E);
  k_row_fused<<<(N + 3)/4, 256, 0, stream>>>(h, coord, col, Wkv, row_start, eidx,
                                             qn, kn, (const unsigned*)vn, aout,
                                             hout, N);
  // qn/kn dead from here: hn overwrites their region
  k_node_hn<<<(N + 127)/128, 256, 0, stream>>>((const unsigned*)vn, w1f, hn, N);
  k_edge_mlp2<<<2048, 256, 0, stream>>>(coord, row, col, Wr6, Wc2,
                                        (const uint4*)hn, eidx2, mlpout, E);
  k_coord<<<(N + 3)/4, 256, 0, stream>>>(coord, col, row_start, eidx, aout,
                                         mlpout, cout, N);
}